// Round 2
// baseline (576.808 us; speedup 1.0000x reference)
//
#include <hip/hip_runtime.h>
#include <cstdint>
#include <cstddef>

// CTC loss forward (mean over batch of loss/target_len), MI355X gfx950.
// Shapes fixed by the reference: log_probs [T=256, B=64, C=8000] f32 (already
// log-softmaxed), targets [B, L=32] i32, input_lengths [B] i32, target_lengths
// [B] i32. Output: 1 float.
//
// Design: one wave per batch (64 blocks x 64 threads). Lane = CTC state s
// (S = 2*32+1 = 65; lane 63 additionally carries s=64 locally). Alpha kept in
// the log2 domain (alpha2 = alpha * log2e) so each step needs no extra muls
// around v_exp_f32/v_log_f32. Emissions are gathered straight from global with
// a depth-16 register ring (inner loop fully unrolled so ring lives in VGPRs).

#define TMAX  256
#define BATCH 64
#define CNUM  8000
#define LMAX  32
#define SDIM  65
#define LOG2E 1.44269504088896340736f
#define LN2   0.69314718055994530942f
#define NEG2  (-1.0e9f * LOG2E)   // reference NEG = -1e9, in log2 domain

// gfx950 hardware base-2 transcendentals (HIP has no __exp2f/__log2f device
// intrinsics; the CUDA spellings collide with glibc math.h host decls).
__device__ __forceinline__ float hexp2(float x) { return __builtin_amdgcn_exp2f(x); }
__device__ __forceinline__ float hlog2(float x) { return __builtin_amdgcn_logf(x); }

__device__ __forceinline__ float lae3_log2(float a, float b, float c) {
    // log2(2^a + 2^b + 2^c), inputs in log2 domain
    float m = fmaxf(fmaxf(a, b), c);                 // v_max3
    float r = hexp2(a - m) + hexp2(b - m) + hexp2(c - m);
    return m + hlog2(r);
}

__global__ __launch_bounds__(64) void ctc_dp(
    const float* __restrict__ lp, const int* __restrict__ targets,
    const int* __restrict__ in_len, const int* __restrict__ tg_len,
    float* __restrict__ partial)
{
    const int b    = blockIdx.x;
    const int lane = threadIdx.x;           // state s = lane (0..63)
    const int Lb   = tg_len[b];
    const int Tb   = in_len[b];

    // Extended-target label for state s = lane; blanks (label 0) on even s.
    int  label = 0;
    bool skip  = false;
    if (lane & 1) {
        int k = lane >> 1;
        label = (k < Lb) ? targets[b * LMAX + k] : 0;
        int prev = (k >= 1) ? ((k - 1 < Lb) ? targets[b * LMAX + (k - 1)] : 0) : -1;
        skip = (label != 0) && (label != prev);
    }
    const bool use2 = skip && (lane >= 2);  // s<2 has no s-2 predecessor

    // Per-lane gather base: lp[t, b, label] = pbase[t * B*C]
    const float*  pbase   = lp + (size_t)b * CNUM + (size_t)label;
    const size_t  tstride = (size_t)BATCH * CNUM;

    // t = 0 init (alpha in log2 domain)
    float em0 = pbase[0];                   // lp[0, b, ext[lane]]
    float a   = NEG2;
    if (lane == 0)            a = em0 * LOG2E;
    if (lane == 1 && Lb > 0)  a = em0 * LOG2E;
    float a64 = NEG2;                       // state s=64 (valid on lane 63)

    const int steps  = Tb - 1;              // >= 128 per setup
    const int chunks = (steps + 15) >> 4;   // run chunks*16 steps, snapshot at t==steps

    // Prime the depth-16 prefetch ring with t = 1..16
    float ring[16];
    #pragma unroll
    for (int i = 0; i < 16; ++i) {
        int tl = 1 + i; if (tl > TMAX - 1) tl = TMAX - 1;
        ring[i] = pbase[(size_t)tl * tstride];
    }

    float a_res = a, a64_res = a64;
    int t = 1;
    for (int c = 0; c < chunks; ++c) {
        #pragma unroll
        for (int i = 0; i < 16; ++i, ++t) {
            float em2  = ring[i] * LOG2E;
            // blank emission for s=64 == lane 0's emission (label 0)
            float em2b = __uint_as_float(
                __builtin_amdgcn_readfirstlane(__float_as_uint(em2)));

            float am1 = __shfl_up(a, 1, 64);
            float am2 = __shfl_up(a, 2, 64);
            am1 = (lane >= 1) ? am1 : NEG2;
            float am2p = use2 ? am2 : NEG2;

            // s=64 update from OLD a64 and OLD a[63] (own value on lane 63);
            // computed on all lanes, only lane 63's result is meaningful.
            float m64  = fmaxf(a64, a);
            float r64  = hexp2(a64 - m64) + hexp2(a - m64);
            float a64n = m64 + hlog2(r64) + em2b;

            a   = lae3_log2(a, am1, am2p) + em2;
            a64 = a64n;

            if (t == steps) { a_res = a; a64_res = a64; }

            // prefetch emission for t+16 (clamped; extra steps past `steps`
            // update garbage that is never read — snapshot already taken)
            int tl = t + 16; if (tl > TMAX - 1) tl = TMAX - 1;
            ring[i] = pbase[(size_t)tl * tstride];
        }
    }

    // Gather final alpha across lanes via LDS, lane 0 finishes the loss.
    __shared__ float fin[SDIM];
    fin[lane] = a_res;
    if (lane == 63) fin[64] = a64_res;
    __syncthreads();

    if (lane == 0) {
        int iB = 2 * Lb;
        int iC = iB - 1; if (iC < 0) iC = 0;
        float vB = fin[iB];
        float vC = fin[iC];
        float tot2;
        if (Lb > 0) {
            float m = fmaxf(vB, vC);
            tot2 = m + hlog2(hexp2(vB - m) + hexp2(vC - m));
        } else {
            tot2 = vB;
        }
        float loss = -(tot2 * LN2);                  // back to natural log
        float sl   = (Lb > 0) ? (float)Lb : 1.0f;
        partial[b] = loss / sl;
    }
}

__global__ __launch_bounds__(64) void ctc_reduce(
    const float* __restrict__ partial, float* __restrict__ out)
{
    float v = partial[threadIdx.x];
    #pragma unroll
    for (int off = 32; off > 0; off >>= 1) v += __shfl_xor(v, off, 64);
    if (threadIdx.x == 0) out[0] = v * (1.0f / BATCH);
}

extern "C" void kernel_launch(void* const* d_in, const int* in_sizes, int n_in,
                              void* d_out, int out_size, void* d_ws, size_t ws_size,
                              hipStream_t stream) {
    const float* lp = (const float*)d_in[0];
    const int*   tg = (const int*)d_in[1];
    const int*   il = (const int*)d_in[2];
    const int*   tl = (const int*)d_in[3];
    float* partial  = (float*)d_ws;        // 64 floats; fully overwritten each call

    ctc_dp<<<dim3(BATCH), dim3(64), 0, stream>>>(lp, tg, il, tl, partial);
    ctc_reduce<<<dim3(1), dim3(64), 0, stream>>>(partial, (float*)d_out);
}